// Round 1
// baseline (67.932 us; speedup 1.0000x reference)
//
#include <hip/hip_runtime.h>
#include <math.h>

// Problem constants
//  x: (64, 4096, 3, 16) f32 -> flat feature dim 48, g=16 groups of 3
//  HEADS=4, ROT_HIDDEN=128, MLP_HIDDEN=256, NUM_CLASSES=12
//  feats: (B, H*3*7) = (64, 84)

#define PI_F 3.14159265358979323846f

// ---------------- Stage A: column mean over T (gf sums) ----------------
// grid 512 = 64 b * 8 t-chunks, block 384 = 8 rows x 48 feats
__global__ __launch_bounds__(384) void k_colmean(const float* __restrict__ x,
                                                 float* __restrict__ gfsum) {
    int b = blockIdx.x >> 3;
    int chunk = blockIdx.x & 7;
    int tid = threadIdx.x;
    int f = tid % 48, r = tid / 48;
    const float* px = x + ((size_t)b * 4096 + (size_t)chunk * 512 + r) * 48 + f;
    float s = 0.f;
#pragma unroll 8
    for (int i = 0; i < 64; ++i) s += px[(size_t)i * 8 * 48];
    __shared__ float red[384];
    red[tid] = s;
    __syncthreads();
    if (tid < 48) {
        float t = 0.f;
#pragma unroll
        for (int rr = 0; rr < 8; ++rr) t += red[rr * 48 + tid];
        atomicAdd(&gfsum[b * 48 + tid], t);
    }
}

// ---------------- Stage B: rotation MLP -> 3x3 matrices ----------------
// grid 64 (one per b), block 128
__global__ __launch_bounds__(128) void k_rot(const float* __restrict__ gfsum,
                                             const float* __restrict__ w1, const float* __restrict__ b1,
                                             const float* __restrict__ w2, const float* __restrict__ b2,
                                             const float* __restrict__ w3, const float* __restrict__ b3,
                                             float* __restrict__ Rmat) {
    int b = blockIdx.x;
    int j = threadIdx.x;
    __shared__ float gf_s[48], h1_s[128], h2_s[128], rot_s[16];
    if (j < 48) gf_s[j] = gfsum[b * 48 + j] * (1.f / 4096.f);
    __syncthreads();
    float a = b1[j];
#pragma unroll
    for (int i = 0; i < 48; ++i) a = fmaf(gf_s[i], w1[i * 128 + j], a);
    h1_s[j] = fmaxf(a, 0.f);
    __syncthreads();
    a = b2[j];
    for (int i = 0; i < 128; ++i) a = fmaf(h1_s[i], w2[i * 128 + j], a);
    h2_s[j] = fmaxf(a, 0.f);
    __syncthreads();
    if (j < 16) {
        a = b3[j];
        for (int i = 0; i < 128; ++i) a = fmaf(h2_s[i], w3[i * 16 + j], a);
        rot_s[j] = tanhf(a);
    }
    __syncthreads();
    if (j < 4) {
        float kx = rot_s[j * 4 + 0], ky = rot_s[j * 4 + 1], kz = rot_s[j * 4 + 2];
        float w = rot_s[j * 4 + 3];
        float nrm = sqrtf(kx * kx + ky * ky + kz * kz) + 1e-8f;
        kx /= nrm; ky /= nrm; kz /= nrm;
        float th = w * PI_F;
        float c = cosf(th), s = sinf(th), C = 1.f - c;
        float* R = Rmat + ((size_t)b * 4 + j) * 9;
        R[0] = c + kx * kx * C;      R[1] = kx * ky * C - kz * s; R[2] = kx * kz * C + ky * s;
        R[3] = ky * kx * C + kz * s; R[4] = c + ky * ky * C;      R[5] = ky * kz * C - kx * s;
        R[6] = kz * kx * C - ky * s; R[7] = kz * ky * C + kx * s; R[8] = c + kz * kz * C;
    }
}

// ---------------- Stage C: fused rotate + hierarchical block stats ----------------
// grid 1024 = 64 b * 16 tiles (256 t-rows each), block 256 = 4 chunks x (4 h x 16 g)
__global__ __launch_bounds__(256) void k_stats(const float* __restrict__ x,
                                               const float* __restrict__ Rmat,
                                               float* __restrict__ acc) {
    __shared__ float xs[256 * 48];  // 48 KB staging, reused as reduction scratch
    int bid = blockIdx.x;
    int b = bid >> 4;
    int tile = bid & 15;
    int tid = threadIdx.x;

    // stage 256 rows x 48 floats (coalesced float4)
    {
        const float4* src = (const float4*)(x + ((size_t)b * 4096 + (size_t)tile * 256) * 48);
        float4* dst = (float4*)xs;
#pragma unroll
        for (int i = 0; i < 12; ++i) dst[tid + 256 * i] = src[tid + 256 * i];
    }

    int grp = tid >> 6;    // which 64-t chunk within the tile
    int lane = tid & 63;
    int g = lane & 15;
    int h = lane >> 4;

    const float* Rp = Rmat + ((size_t)(b * 4 + h)) * 9;
    float R0 = Rp[0], R1 = Rp[1], R2 = Rp[2];
    float R3 = Rp[3], R4 = Rp[4], R5 = Rp[5];
    float R6 = Rp[6], R7 = Rp[7], R8 = Rp[8];

    __syncthreads();

    const float* rowp = xs + (grp * 64) * 48 + 3 * g;

    // accumulators: [s*7+q], s in {16,32,64}, q = mean,std,min,max,rms,mac,energy
    float a21[21];
#pragma unroll
    for (int i = 0; i < 21; ++i) a21[i] = 0.f;

    float p32s[3] = {0, 0, 0}, p32q[3] = {0, 0, 0}, p32n[3], p32x[3], p32m[3] = {0, 0, 0};
    float p64s[3] = {0, 0, 0}, p64q[3] = {0, 0, 0}, p64n[3], p64x[3], p64m[3] = {0, 0, 0};
#pragma unroll
    for (int c = 0; c < 3; ++c) { p32n[c] = 1e30f; p32x[c] = -1e30f; p64n[c] = 1e30f; p64x[c] = -1e30f; }
    float prev[3];

#pragma unroll
    for (int k = 0; k < 4; ++k) {
        float cs[3], cq[3], cn[3], cx[3], cm[3];
        {   // first element of the 16-block
            const float* p = rowp + (k * 16) * 48;
            float v0 = p[0], v1 = p[1], v2 = p[2];
            float yy[3];
            yy[0] = R0 * v0 + R1 * v1 + R2 * v2;
            yy[1] = R3 * v0 + R4 * v1 + R5 * v2;
            yy[2] = R6 * v0 + R7 * v1 + R8 * v2;
#pragma unroll
            for (int c = 0; c < 3; ++c) {
                float y = yy[c];
                if (k > 0) {  // block-boundary diff for the larger block sizes
                    float bd = fabsf(y - prev[c]);
                    if (k != 2) p32m[c] += bd;   // t=16,48: inside a 32-block
                    p64m[c] += bd;               // t=16,32,48: inside the 64-block
                }
                cs[c] = y; cq[c] = y * y; cn[c] = y; cx[c] = y; cm[c] = 0.f; prev[c] = y;
            }
        }
#pragma unroll
        for (int t = 1; t < 16; ++t) {
            const float* p = rowp + (k * 16 + t) * 48;
            float v0 = p[0], v1 = p[1], v2 = p[2];
            float yy[3];
            yy[0] = R0 * v0 + R1 * v1 + R2 * v2;
            yy[1] = R3 * v0 + R4 * v1 + R5 * v2;
            yy[2] = R6 * v0 + R7 * v1 + R8 * v2;
#pragma unroll
            for (int c = 0; c < 3; ++c) {
                float y = yy[c];
                cs[c] += y;
                cq[c] = fmaf(y, y, cq[c]);
                cn[c] = fminf(cn[c], y);
                cx[c] = fmaxf(cx[c], y);
                cm[c] += fabsf(y - prev[c]);
                prev[c] = y;
            }
        }
        // finalize 16-block, fold into 32
#pragma unroll
        for (int c = 0; c < 3; ++c) {
            float mean = cs[c] * (1.f / 16.f);
            float m2 = cq[c] * (1.f / 16.f);
            a21[0] += cs[c];
            a21[1] += sqrtf(fmaxf(m2 - mean * mean, 0.f));
            a21[2] += cn[c];
            a21[3] += cx[c];
            a21[4] += sqrtf(m2 + 1e-8f);
            a21[5] += cm[c];
            a21[6] += cq[c];
            p32s[c] += cs[c]; p32q[c] += cq[c];
            p32n[c] = fminf(p32n[c], cn[c]); p32x[c] = fmaxf(p32x[c], cx[c]); p32m[c] += cm[c];
        }
        if (k & 1) {  // finalize 32-block, fold into 64
#pragma unroll
            for (int c = 0; c < 3; ++c) {
                float mean = p32s[c] * (1.f / 32.f);
                float m2 = p32q[c] * (1.f / 32.f);
                a21[7] += p32s[c];
                a21[8] += sqrtf(fmaxf(m2 - mean * mean, 0.f));
                a21[9] += p32n[c];
                a21[10] += p32x[c];
                a21[11] += sqrtf(m2 + 1e-8f);
                a21[12] += p32m[c];
                a21[13] += p32q[c];
                p64s[c] += p32s[c]; p64q[c] += p32q[c];
                p64n[c] = fminf(p64n[c], p32n[c]); p64x[c] = fmaxf(p64x[c], p32x[c]); p64m[c] += p32m[c];
                p32s[c] = 0.f; p32q[c] = 0.f; p32n[c] = 1e30f; p32x[c] = -1e30f; p32m[c] = 0.f;
            }
        }
    }
    // finalize 64-block
#pragma unroll
    for (int c = 0; c < 3; ++c) {
        float mean = p64s[c] * (1.f / 64.f);
        float m2 = p64q[c] * (1.f / 64.f);
        a21[14] += p64s[c];
        a21[15] += sqrtf(fmaxf(m2 - mean * mean, 0.f));
        a21[16] += p64n[c];
        a21[17] += p64x[c];
        a21[18] += sqrtf(m2 + 1e-8f);
        a21[19] += p64m[c];
        a21[20] += p64q[c];
    }

    // block reduction over (chunk, g) per (h, s, q), then atomic into acc[b][84]
    __syncthreads();
    float* red = xs;  // reuse staging (needs 256*21*4 = 21.5 KB <= 48 KB)
#pragma unroll
    for (int q = 0; q < 21; ++q) red[tid * 21 + q] = a21[q];
    __syncthreads();
    if (tid < 84) {
        int hh = tid / 21, sq = tid % 21;
        float s = 0.f;
        for (int u = 0; u < 64; ++u) {
            int src_t = (u >> 4) * 64 + hh * 16 + (u & 15);
            s += red[src_t * 21 + sq];
        }
        atomicAdd(&acc[b * 84 + tid], s);
    }
}

// ---------------- Stage D: classifier MLP head ----------------
// grid 64 (one per b), block 256
__global__ __launch_bounds__(256) void k_head(const float* __restrict__ acc,
                                              const float* __restrict__ p1, const float* __restrict__ pb1,
                                              const float* __restrict__ p2, const float* __restrict__ pb2,
                                              const float* __restrict__ p3, const float* __restrict__ pb3,
                                              float* __restrict__ out) {
    int b = blockIdx.x, j = threadIdx.x;
    __shared__ float feat_s[84], q1_s[256], q2_s[256];
    if (j < 84) {
        int s = (j % 21) / 7;
        int q = j % 7;
        float bs = (float)(16 << s);
        float n = 4096.f / bs;
        float base = n * 48.f;
        float divi;
        if (q == 0 || q == 6) divi = base * bs;        // mean, energy (raw sum / sumsq)
        else if (q == 5) divi = base * (bs - 1.f);     // mac (raw |diff| sums)
        else divi = base;                              // std, min, max, rms (finalized per block)
        feat_s[j] = acc[b * 84 + j] / divi;
    }
    __syncthreads();
    float a = pb1[j];
#pragma unroll
    for (int i = 0; i < 84; ++i) a = fmaf(feat_s[i], p1[i * 256 + j], a);
    q1_s[j] = fmaxf(a, 0.f);
    __syncthreads();
    a = pb2[j];
    for (int i = 0; i < 256; ++i) a = fmaf(q1_s[i], p2[i * 256 + j], a);
    q2_s[j] = fmaxf(a, 0.f);
    __syncthreads();
    if (j < 12) {
        a = pb3[j];
        for (int i = 0; i < 256; ++i) a = fmaf(q2_s[i], p3[i * 12 + j], a);
        out[b * 12 + j] = a;
    }
}

extern "C" void kernel_launch(void* const* d_in, const int* in_sizes, int n_in,
                              void* d_out, int out_size, void* d_ws, size_t ws_size,
                              hipStream_t stream) {
    const float* x  = (const float*)d_in[0];
    const float* w1 = (const float*)d_in[1];
    const float* b1 = (const float*)d_in[2];
    const float* w2 = (const float*)d_in[3];
    const float* b2 = (const float*)d_in[4];
    const float* w3 = (const float*)d_in[5];
    const float* b3 = (const float*)d_in[6];
    const float* p1 = (const float*)d_in[7];
    const float* pb1 = (const float*)d_in[8];
    const float* p2 = (const float*)d_in[9];
    const float* pb2 = (const float*)d_in[10];
    const float* p3 = (const float*)d_in[11];
    const float* pb3 = (const float*)d_in[12];

    float* ws = (float*)d_ws;
    float* gfsum = ws;          // 64*48  = 3072 floats
    float* acc   = ws + 3072;   // 64*84  = 5376 floats
    float* Rmat  = ws + 8448;   // 64*4*9 = 2304 floats

    // zero the atomic accumulators (gfsum + acc) every call
    hipMemsetAsync(d_ws, 0, 8448 * sizeof(float), stream);

    k_colmean<<<512, 384, 0, stream>>>(x, gfsum);
    k_rot<<<64, 128, 0, stream>>>(gfsum, w1, b1, w2, b2, w3, b3, Rmat);
    k_stats<<<1024, 256, 0, stream>>>(x, Rmat, acc);
    k_head<<<64, 256, 0, stream>>>(acc, p1, pb1, p2, pb2, p3, pb3, (float*)d_out);
}

// Round 2
// 63.575 us; speedup vs baseline: 1.0685x; 1.0685x over previous
//
#include <hip/hip_runtime.h>
#include <math.h>

// Problem constants
//  x: (64, 4096, 3, 16) f32 -> flat feature dim 48, g=16 groups of 3
//  HEADS=4, ROT_HIDDEN=128, MLP_HIDDEN=256, NUM_CLASSES=12
//  feats: (B, H*3*7) = (64, 84)

#define PI_F 3.14159265358979323846f

// ---------------- Stage A: column partial-sums over T ----------------
// grid 512 = 64 b * 8 chunks (512 rows each), block 384 = 32 rows x 12 float4
// Writes gfpart[(b*8+chunk)*48 + f] -- no atomics, no pre-zero needed.
__global__ __launch_bounds__(384) void k_colmean(const float4* __restrict__ x4,
                                                 float* __restrict__ gfpart) {
    int b = blockIdx.x >> 3;
    int chunk = blockIdx.x & 7;
    int tid = threadIdx.x;
    int j4 = tid % 12, r = tid / 12;  // r in [0,32)
    const float4* p = x4 + ((size_t)(b * 4096 + chunk * 512 + r)) * 12 + j4;
    float4 s = make_float4(0.f, 0.f, 0.f, 0.f);
#pragma unroll
    for (int i = 0; i < 16; ++i) {
        float4 v = p[(size_t)i * 32 * 12];
        s.x += v.x; s.y += v.y; s.z += v.z; s.w += v.w;
    }
    __shared__ float4 red[384];
    red[tid] = s;
    __syncthreads();
    if (tid < 48) {
        int jj = tid >> 2, c = tid & 3;
        float t = 0.f;
#pragma unroll
        for (int rr = 0; rr < 32; ++rr) {
            const float* q = (const float*)&red[rr * 12 + jj];
            t += q[c];
        }
        gfpart[blockIdx.x * 48 + tid] = t;
    }
}

// ---------------- Stage B: rotation MLP -> 3x3 matrices ----------------
// grid 64 (one per b), block 128
__global__ __launch_bounds__(128) void k_rot(const float* __restrict__ gfpart,
                                             const float* __restrict__ w1, const float* __restrict__ b1,
                                             const float* __restrict__ w2, const float* __restrict__ b2,
                                             const float* __restrict__ w3, const float* __restrict__ b3,
                                             float* __restrict__ Rmat) {
    int b = blockIdx.x;
    int j = threadIdx.x;
    __shared__ float gf_s[48], h1_s[128], h2_s[128], rot_s[16];
    if (j < 48) {
        float s = 0.f;
#pragma unroll
        for (int ch = 0; ch < 8; ++ch) s += gfpart[(b * 8 + ch) * 48 + j];
        gf_s[j] = s * (1.f / 4096.f);
    }
    __syncthreads();
    float a = b1[j];
#pragma unroll
    for (int i = 0; i < 48; ++i) a = fmaf(gf_s[i], w1[i * 128 + j], a);
    h1_s[j] = fmaxf(a, 0.f);
    __syncthreads();
    a = b2[j];
    for (int i = 0; i < 128; ++i) a = fmaf(h1_s[i], w2[i * 128 + j], a);
    h2_s[j] = fmaxf(a, 0.f);
    __syncthreads();
    if (j < 16) {
        a = b3[j];
        for (int i = 0; i < 128; ++i) a = fmaf(h2_s[i], w3[i * 16 + j], a);
        rot_s[j] = tanhf(a);
    }
    __syncthreads();
    if (j < 4) {
        float kx = rot_s[j * 4 + 0], ky = rot_s[j * 4 + 1], kz = rot_s[j * 4 + 2];
        float w = rot_s[j * 4 + 3];
        float nrm = sqrtf(kx * kx + ky * ky + kz * kz) + 1e-8f;
        kx /= nrm; ky /= nrm; kz /= nrm;
        float th = w * PI_F;
        float c = cosf(th), s = sinf(th), C = 1.f - c;
        float* R = Rmat + ((size_t)b * 4 + j) * 9;
        R[0] = c + kx * kx * C;      R[1] = kx * ky * C - kz * s; R[2] = kx * kz * C + ky * s;
        R[3] = ky * kx * C + kz * s; R[4] = c + ky * ky * C;      R[5] = ky * kz * C - kx * s;
        R[6] = kz * kx * C - ky * s; R[7] = kz * ky * C + kx * s; R[8] = c + kz * kz * C;
    }
}

// ---------------- Stage C: fused rotate + hierarchical block stats ----------------
// grid 1024 = 64 b * 16 tiles (256 t-rows each), block 256 = 4 chunks x (4 h x 16 g)
// Writes accpart[(b*16+tile)*84 + j] -- no atomics.
__global__ __launch_bounds__(256) void k_stats(const float* __restrict__ x,
                                               const float* __restrict__ Rmat,
                                               float* __restrict__ accpart) {
    __shared__ float xs[256 * 48];  // 48 KB staging, reused as reduction scratch
    int bid = blockIdx.x;
    int b = bid >> 4;
    int tile = bid & 15;
    int tid = threadIdx.x;

    // stage 256 rows x 48 floats (coalesced float4)
    {
        const float4* src = (const float4*)(x + ((size_t)b * 4096 + (size_t)tile * 256) * 48);
        float4* dst = (float4*)xs;
#pragma unroll
        for (int i = 0; i < 12; ++i) dst[tid + 256 * i] = src[tid + 256 * i];
    }

    int grp = tid >> 6;    // which 64-t chunk within the tile
    int lane = tid & 63;
    int g = lane & 15;
    int h = lane >> 4;

    const float* Rp = Rmat + ((size_t)(b * 4 + h)) * 9;
    float R0 = Rp[0], R1 = Rp[1], R2 = Rp[2];
    float R3 = Rp[3], R4 = Rp[4], R5 = Rp[5];
    float R6 = Rp[6], R7 = Rp[7], R8 = Rp[8];

    __syncthreads();

    const float* rowp = xs + (grp * 64) * 48 + 3 * g;

    // accumulators: [s*7+q], s in {16,32,64}, q = mean,std,min,max,rms,mac,energy
    float a21[21];
#pragma unroll
    for (int i = 0; i < 21; ++i) a21[i] = 0.f;

    float p32s[3] = {0, 0, 0}, p32q[3] = {0, 0, 0}, p32n[3], p32x[3], p32m[3] = {0, 0, 0};
    float p64s[3] = {0, 0, 0}, p64q[3] = {0, 0, 0}, p64n[3], p64x[3], p64m[3] = {0, 0, 0};
#pragma unroll
    for (int c = 0; c < 3; ++c) { p32n[c] = 1e30f; p32x[c] = -1e30f; p64n[c] = 1e30f; p64x[c] = -1e30f; }
    float prev[3];

#pragma unroll
    for (int k = 0; k < 4; ++k) {
        float cs[3], cq[3], cn[3], cx[3], cm[3];
        {   // first element of the 16-block
            const float* p = rowp + (k * 16) * 48;
            float v0 = p[0], v1 = p[1], v2 = p[2];
            float yy[3];
            yy[0] = R0 * v0 + R1 * v1 + R2 * v2;
            yy[1] = R3 * v0 + R4 * v1 + R5 * v2;
            yy[2] = R6 * v0 + R7 * v1 + R8 * v2;
#pragma unroll
            for (int c = 0; c < 3; ++c) {
                float y = yy[c];
                if (k > 0) {  // block-boundary diff for the larger block sizes
                    float bd = fabsf(y - prev[c]);
                    if (k != 2) p32m[c] += bd;   // t=16,48: inside a 32-block
                    p64m[c] += bd;               // t=16,32,48: inside the 64-block
                }
                cs[c] = y; cq[c] = y * y; cn[c] = y; cx[c] = y; cm[c] = 0.f; prev[c] = y;
            }
        }
#pragma unroll
        for (int t = 1; t < 16; ++t) {
            const float* p = rowp + (k * 16 + t) * 48;
            float v0 = p[0], v1 = p[1], v2 = p[2];
            float yy[3];
            yy[0] = R0 * v0 + R1 * v1 + R2 * v2;
            yy[1] = R3 * v0 + R4 * v1 + R5 * v2;
            yy[2] = R6 * v0 + R7 * v1 + R8 * v2;
#pragma unroll
            for (int c = 0; c < 3; ++c) {
                float y = yy[c];
                cs[c] += y;
                cq[c] = fmaf(y, y, cq[c]);
                cn[c] = fminf(cn[c], y);
                cx[c] = fmaxf(cx[c], y);
                cm[c] += fabsf(y - prev[c]);
                prev[c] = y;
            }
        }
        // finalize 16-block, fold into 32
#pragma unroll
        for (int c = 0; c < 3; ++c) {
            float mean = cs[c] * (1.f / 16.f);
            float m2 = cq[c] * (1.f / 16.f);
            a21[0] += cs[c];
            a21[1] += sqrtf(fmaxf(m2 - mean * mean, 0.f));
            a21[2] += cn[c];
            a21[3] += cx[c];
            a21[4] += sqrtf(m2 + 1e-8f);
            a21[5] += cm[c];
            a21[6] += cq[c];
            p32s[c] += cs[c]; p32q[c] += cq[c];
            p32n[c] = fminf(p32n[c], cn[c]); p32x[c] = fmaxf(p32x[c], cx[c]); p32m[c] += cm[c];
        }
        if (k & 1) {  // finalize 32-block, fold into 64
#pragma unroll
            for (int c = 0; c < 3; ++c) {
                float mean = p32s[c] * (1.f / 32.f);
                float m2 = p32q[c] * (1.f / 32.f);
                a21[7] += p32s[c];
                a21[8] += sqrtf(fmaxf(m2 - mean * mean, 0.f));
                a21[9] += p32n[c];
                a21[10] += p32x[c];
                a21[11] += sqrtf(m2 + 1e-8f);
                a21[12] += p32m[c];
                a21[13] += p32q[c];
                p64s[c] += p32s[c]; p64q[c] += p32q[c];
                p64n[c] = fminf(p64n[c], p32n[c]); p64x[c] = fmaxf(p64x[c], p32x[c]); p64m[c] += p32m[c];
                p32s[c] = 0.f; p32q[c] = 0.f; p32n[c] = 1e30f; p32x[c] = -1e30f; p32m[c] = 0.f;
            }
        }
    }
    // finalize 64-block
#pragma unroll
    for (int c = 0; c < 3; ++c) {
        float mean = p64s[c] * (1.f / 64.f);
        float m2 = p64q[c] * (1.f / 64.f);
        a21[14] += p64s[c];
        a21[15] += sqrtf(fmaxf(m2 - mean * mean, 0.f));
        a21[16] += p64n[c];
        a21[17] += p64x[c];
        a21[18] += sqrtf(m2 + 1e-8f);
        a21[19] += p64m[c];
        a21[20] += p64q[c];
    }

    // block reduction over (chunk, g) per (h, s, q), then store partial
    __syncthreads();
    float* red = xs;  // reuse staging (needs 256*21*4 = 21.5 KB <= 48 KB)
#pragma unroll
    for (int q = 0; q < 21; ++q) red[tid * 21 + q] = a21[q];
    __syncthreads();
    if (tid < 84) {
        int hh = tid / 21, sq = tid % 21;
        float s = 0.f;
        for (int u = 0; u < 64; ++u) {
            int src_t = (u >> 4) * 64 + hh * 16 + (u & 15);
            s += red[src_t * 21 + sq];
        }
        accpart[bid * 84 + tid] = s;
    }
}

// ---------------- Stage D: classifier MLP head ----------------
// grid 64 (one per b), block 256
__global__ __launch_bounds__(256) void k_head(const float* __restrict__ accpart,
                                              const float* __restrict__ p1, const float* __restrict__ pb1,
                                              const float* __restrict__ p2, const float* __restrict__ pb2,
                                              const float* __restrict__ p3, const float* __restrict__ pb3,
                                              float* __restrict__ out) {
    int b = blockIdx.x, j = threadIdx.x;
    __shared__ float feat_s[84], q1_s[256], q2_s[256];
    if (j < 84) {
        float raw = 0.f;
#pragma unroll
        for (int t = 0; t < 16; ++t) raw += accpart[(b * 16 + t) * 84 + j];
        int s = (j % 21) / 7;
        int q = j % 7;
        float bs = (float)(16 << s);
        float n = 4096.f / bs;
        float base = n * 48.f;
        float divi;
        if (q == 0 || q == 6) divi = base * bs;        // mean, energy (raw sum / sumsq)
        else if (q == 5) divi = base * (bs - 1.f);     // mac (raw |diff| sums)
        else divi = base;                              // std, min, max, rms (finalized per block)
        feat_s[j] = raw / divi;
    }
    __syncthreads();
    float a = pb1[j];
#pragma unroll
    for (int i = 0; i < 84; ++i) a = fmaf(feat_s[i], p1[i * 256 + j], a);
    q1_s[j] = fmaxf(a, 0.f);
    __syncthreads();
    a = pb2[j];
    for (int i = 0; i < 256; ++i) a = fmaf(q1_s[i], p2[i * 256 + j], a);
    q2_s[j] = fmaxf(a, 0.f);
    __syncthreads();
    if (j < 12) {
        a = pb3[j];
        for (int i = 0; i < 256; ++i) a = fmaf(q2_s[i], p3[i * 12 + j], a);
        out[b * 12 + j] = a;
    }
}

extern "C" void kernel_launch(void* const* d_in, const int* in_sizes, int n_in,
                              void* d_out, int out_size, void* d_ws, size_t ws_size,
                              hipStream_t stream) {
    const float* x  = (const float*)d_in[0];
    const float* w1 = (const float*)d_in[1];
    const float* b1 = (const float*)d_in[2];
    const float* w2 = (const float*)d_in[3];
    const float* b2 = (const float*)d_in[4];
    const float* w3 = (const float*)d_in[5];
    const float* b3 = (const float*)d_in[6];
    const float* p1 = (const float*)d_in[7];
    const float* pb1 = (const float*)d_in[8];
    const float* p2 = (const float*)d_in[9];
    const float* pb2 = (const float*)d_in[10];
    const float* p3 = (const float*)d_in[11];
    const float* pb3 = (const float*)d_in[12];

    float* ws = (float*)d_ws;
    float* gfpart  = ws;             // 64*8*48   = 24576 floats
    float* Rmat    = ws + 24576;     // 64*4*9    = 2304 floats
    float* accpart = ws + 26880;     // 64*16*84  = 86016 floats

    k_colmean<<<512, 384, 0, stream>>>((const float4*)x, gfpart);
    k_rot<<<64, 128, 0, stream>>>(gfpart, w1, b1, w2, b2, w3, b3, Rmat);
    k_stats<<<1024, 256, 0, stream>>>(x, Rmat, accpart);
    k_head<<<64, 256, 0, stream>>>(accpart, p1, pb1, p2, pb2, p3, pb3, (float*)d_out);
}